// Round 1
// baseline (102.718 us; speedup 1.0000x reference)
//
#include <hip/hip_runtime.h>

#define BB 2
#define NN 512
#define INF 10
#define FPAD 260   // 256 + 4 pad floats; row stride 1040B -> bank rotation 4*row mod 32

static __device__ __forceinline__ float dot4(float4 w, float4 v, float acc) {
    acc = fmaf(w.x, v.x, acc);
    acc = fmaf(w.y, v.y, acc);
    acc = fmaf(w.z, v.z, acc);
    acc = fmaf(w.w, v.w, acc);
    return acc;
}

// Kernel 1: per-point MLP chain (10->128->128->64) + projections to ha[256], hb[256]+bp0.
// 256 blocks x 256 threads, 4 points per block. Outputs f-contiguous: haT[point][f].
__global__ __launch_bounds__(256) void k_points(
    const float* __restrict__ x,
    const float* __restrict__ Ws0, const float* __restrict__ bs0,
    const float* __restrict__ Ws1, const float* __restrict__ bs1,
    const float* __restrict__ Ws2, const float* __restrict__ bs2,
    const float* __restrict__ Wp0, const float* __restrict__ bp0,
    float* __restrict__ haT, float* __restrict__ hbT)
{
    __shared__ __align__(16) float xs[4][INF];
    __shared__ __align__(16) float u0s[4][128];
    __shared__ __align__(16) float u1s[4][128];
    __shared__ __align__(16) float u2s[4][64];

    const int t  = threadIdx.x;
    const int p0 = blockIdx.x * 4;   // flat point index b*N+n (4 points, same batch)

    // load x for 4 points
    if (t < 4 * INF) {
        int p = t / INF, c = t % INF;
        xs[p][c] = x[(p0 + p) * INF + c];
    }
    __syncthreads();

    // layer 0: 10 -> 128 (thread t: f = t&127, two points ph*2+{0,1})
    {
        const int f = t & 127, ph = t >> 7;
        float a0 = bs0[f], a1 = a0;
        #pragma unroll
        for (int c = 0; c < INF; ++c) {
            float w = Ws0[f * INF + c];
            a0 = fmaf(w, xs[ph * 2 + 0][c], a0);
            a1 = fmaf(w, xs[ph * 2 + 1][c], a1);
        }
        u0s[ph * 2 + 0][f] = fmaxf(a0, 0.f);
        u0s[ph * 2 + 1][f] = fmaxf(a1, 0.f);
    }
    __syncthreads();

    // layer 1: 128 -> 128
    {
        const int f = t & 127, ph = t >> 7;
        float a0 = bs1[f], a1 = a0;
        const float4* wv = (const float4*)(Ws1 + f * 128);
        #pragma unroll 8
        for (int c4 = 0; c4 < 32; ++c4) {
            float4 w  = wv[c4];
            float4 x0 = *(const float4*)&u0s[ph * 2 + 0][c4 * 4];
            float4 x1 = *(const float4*)&u0s[ph * 2 + 1][c4 * 4];
            a0 = dot4(w, x0, a0);
            a1 = dot4(w, x1, a1);
        }
        u1s[ph * 2 + 0][f] = fmaxf(a0, 0.f);
        u1s[ph * 2 + 1][f] = fmaxf(a1, 0.f);
    }
    __syncthreads();

    // layer 2: 128 -> 64 (thread t: f = t&63, point p = t>>6)
    {
        const int f = t & 63, p = t >> 6;
        float a = bs2[f];
        const float4* wv = (const float4*)(Ws2 + f * 128);
        #pragma unroll 8
        for (int c4 = 0; c4 < 32; ++c4) {
            float4 w  = wv[c4];
            float4 xv = *(const float4*)&u1s[p][c4 * 4];
            a = dot4(w, xv, a);
        }
        u2s[p][f] = fmaxf(a, 0.f);
    }
    __syncthreads();

    // projection: f = t (0..255); ha[f] = Wa[f,:]@u2, hb[f] = Wb[f,:]@u2 + bp0[f], 4 points each
    {
        const int f = t;
        float ah[4], bh[4];
        const float bb = bp0[f];
        #pragma unroll
        for (int p = 0; p < 4; ++p) { ah[p] = 0.f; bh[p] = bb; }
        const float4* wv = (const float4*)(Wp0 + f * 128);
        #pragma unroll 4
        for (int c4 = 0; c4 < 16; ++c4) {
            float4 wa = wv[c4];
            float4 wb = wv[16 + c4];
            #pragma unroll
            for (int p = 0; p < 4; ++p) {
                float4 u = *(const float4*)&u2s[p][c4 * 4];
                ah[p] = dot4(wa, u, ah[p]);
                bh[p] = dot4(wb, u, bh[p]);
            }
        }
        #pragma unroll
        for (int p = 0; p < 4; ++p) {
            haT[(size_t)(p0 + p) * 256 + f] = ah[p];
            hbT[(size_t)(p0 + p) * 256 + f] = bh[p];
        }
    }
}

// Kernel 2: out[b,i,j] = bp1 + sum_f w[f]*relu(ha[b,f,j] + hbc[b,f,i])
// grid (16,16,2): 32x32 tile per block; 4 waves as 2x2; lane = 8x8; 2x2 regs/thread.
__global__ __launch_bounds__(256) void k_outer(
    const float* __restrict__ haT, const float* __restrict__ hbT,
    const float* __restrict__ Wp1, const float* __restrict__ bp1,
    float* __restrict__ out)
{
    __shared__ __align__(16) float sA[32][FPAD];  // ha, local j
    __shared__ __align__(16) float sB[32][FPAD];  // hbc, local i
    __shared__ __align__(16) float sW[256];

    const int t  = threadIdx.x;
    const int jb = blockIdx.x * 32;
    const int ib = blockIdx.y * 32;
    const int b  = blockIdx.z;

    // stage: 32 rows x 256 f per array; f-contiguous float4, coalesced
    const float4* gA = (const float4*)(haT + ((size_t)b * NN + jb) * 256);
    const float4* gB = (const float4*)(hbT + ((size_t)b * NN + ib) * 256);
    #pragma unroll
    for (int k = 0; k < 8; ++k) {
        int idx = t + 256 * k;          // 0..2047
        int row = idx >> 6, f4 = idx & 63;
        float4 va = gA[row * 64 + f4];
        float4 vb = gB[row * 64 + f4];
        *(float4*)&sA[row][f4 * 4] = va;
        *(float4*)&sB[row][f4 * 4] = vb;
    }
    if (t < 64) *(float4*)&sW[t * 4] = ((const float4*)Wp1)[t];
    __syncthreads();

    const int lane = t & 63, wid = t >> 6;
    const int li = lane >> 3, lj = lane & 7;
    const int wr = wid >> 1, wc = wid & 1;
    const int i0 = wr * 16 + li * 2;    // local i of acc row 0
    const int j0 = wc * 16 + lj * 2;    // local j of acc col 0

    const float* A0 = &sA[j0][0];
    const float* A1 = &sA[j0 + 1][0];
    const float* B0 = &sB[i0][0];
    const float* B1 = &sB[i0 + 1][0];

    float acc00 = 0.f, acc01 = 0.f, acc10 = 0.f, acc11 = 0.f;

#define STEP(comp)                                                     \
    {                                                                  \
        float wk = w.comp;                                             \
        acc00 = fmaf(wk, fmaxf(a0.comp + b0.comp, 0.f), acc00);        \
        acc01 = fmaf(wk, fmaxf(a1.comp + b0.comp, 0.f), acc01);        \
        acc10 = fmaf(wk, fmaxf(a0.comp + b1.comp, 0.f), acc10);        \
        acc11 = fmaf(wk, fmaxf(a1.comp + b1.comp, 0.f), acc11);        \
    }

    #pragma unroll 4
    for (int f = 0; f < 256; f += 4) {
        float4 a0 = *(const float4*)(A0 + f);
        float4 a1 = *(const float4*)(A1 + f);
        float4 b0 = *(const float4*)(B0 + f);
        float4 b1 = *(const float4*)(B1 + f);
        float4 w  = *(const float4*)(sW + f);
        STEP(x) STEP(y) STEP(z) STEP(w)
    }
#undef STEP

    const float bv = bp1[0];
    const int gi = ib + i0, gj = jb + j0;
    float* o = out + (size_t)b * NN * NN;
    float2 r0 = { acc00 + bv, acc01 + bv };
    float2 r1 = { acc10 + bv, acc11 + bv };
    *(float2*)&o[(size_t)gi * NN + gj]       = r0;
    *(float2*)&o[(size_t)(gi + 1) * NN + gj] = r1;
}

extern "C" void kernel_launch(void* const* d_in, const int* in_sizes, int n_in,
                              void* d_out, int out_size, void* d_ws, size_t ws_size,
                              hipStream_t stream) {
    const float* x   = (const float*)d_in[0];
    const float* Ws0 = (const float*)d_in[1];
    const float* bs0 = (const float*)d_in[2];
    const float* Ws1 = (const float*)d_in[3];
    const float* bs1 = (const float*)d_in[4];
    const float* Ws2 = (const float*)d_in[5];
    const float* bs2 = (const float*)d_in[6];
    const float* Wp0 = (const float*)d_in[7];
    const float* bp0 = (const float*)d_in[8];
    const float* Wp1 = (const float*)d_in[9];
    const float* bp1 = (const float*)d_in[10];

    float* haT = (float*)d_ws;                       // [B*N][256]
    float* hbT = haT + (size_t)BB * NN * 256;        // [B*N][256]

    k_points<<<dim3(BB * NN / 4), dim3(256), 0, stream>>>(
        x, Ws0, bs0, Ws1, bs1, Ws2, bs2, Wp0, bp0, haT, hbT);

    k_outer<<<dim3(NN / 32, NN / 32, BB), dim3(256), 0, stream>>>(
        haT, hbT, Wp1, bp1, (float*)d_out);
}